// Round 10
// baseline (137.920 us; speedup 1.0000x reference)
//
#include <hip/hip_runtime.h>

#define L_LEN 8192
#define N_FFT 16384   // 2*L
#define NB    512     // each thread packs old-threads (t, t+512): SoA pairs

// LDS (128 KiB) -> 1 block/CU -> 8 waves/CU = 2 waves/EU; declare it so the
// allocator gets the full 256-VGPR budget (pair-SoA needs ~110 live).
#define LB __launch_bounds__(NB, 2)

typedef float f2 __attribute__((ext_vector_type(2)));

// packed complex-pair: re = (re_a, re_b), im = (im_a, im_b) of two INDEPENDENT
// points. Every op below is componentwise -> clean v_pk_* codegen, no op_sel.
struct cpx { f2 re, im; };

__device__ __forceinline__ f2 bc(float s) { f2 v; v.x = s; v.y = s; return v; }
__device__ __forceinline__ f2 mk2(float a, float b) { f2 v; v.x = a; v.y = b; return v; }

__device__ __forceinline__ cpx cadd(cpx a, cpx b) { return {a.re + b.re, a.im + b.im}; }
__device__ __forceinline__ cpx csub(cpx a, cpx b) { return {a.re - b.re, a.im - b.im}; }
__device__ __forceinline__ cpx cmul(cpx a, cpx w) {
    return {a.re * w.re - a.im * w.im, a.re * w.im + a.im * w.re};
}
__device__ __forceinline__ cpx addmi(cpx a, cpx b) { return {a.re + b.im, a.im - b.re}; } // a - i*b
__device__ __forceinline__ cpx addpi(cpx a, cpx b) { return {a.re - b.im, a.im + b.re}; } // a + i*b

// ---- LDS layout: 256B blocks = 32 re-words then 32 im-words. GF(2)-linear
// word index with bank hash; wrd(a^b)=wrd(a)^wrd(b) for disjoint bit fields.
__host__ __device__ constexpr int wrd(int i) {
    return ((i & ~31) << 1) | ((i ^ (i >> 5) ^ (i >> 10)) & 31);
}
// constants: wrd(8192)=16392 (middle-pass half offset), wrd(512)=1040 (first/last)

__device__ __forceinline__ cpx ldsld(const float* lds, int wA, int wB) {
    cpx v;
    v.re.x = lds[wA];      v.re.y = lds[wB];
    v.im.x = lds[wA ^ 32]; v.im.y = lds[wB ^ 32];
    return v;
}
__device__ __forceinline__ void ldsst(float* lds, int wA, int wB, cpx v) {
    lds[wA] = v.re.x;      lds[wB] = v.re.y;
    lds[wA ^ 32] = v.im.x; lds[wB ^ 32] = v.im.y;
}

// reverse 6 base-4 digits
__device__ __forceinline__ int rev4_12(int m) {
    int r = 0;
#pragma unroll
    for (int d = 0; d < 6; ++d) { r = (r << 2) | (m & 3); m >>= 2; }
    return r;
}

// DIF radix-4 (negative-angle twiddles precomputed by caller)
__device__ __forceinline__ void bfly_dif(cpx& x0, cpx& x1, cpx& x2, cpx& x3,
                                         cpx w1, cpx w2, cpx w3) {
    cpx A = cadd(x0, x2), B = csub(x0, x2), C = cadd(x1, x3), D = csub(x1, x3);
    x0 = cadd(A, C);
    x1 = cmul(addmi(B, D), w1);
    x2 = cmul(csub(A, C), w2);
    x3 = cmul(addpi(B, D), w3);
}
// DIT radix-4
__device__ __forceinline__ void bfly_dit(cpx& x0, cpx& x1, cpx& x2, cpx& x3,
                                         cpx w1, cpx w2, cpx w3) {
    cpx a1 = cmul(x1, w1), a2 = cmul(x2, w2), a3 = cmul(x3, w3);
    cpx E = cadd(x0, a2), F = csub(x0, a2), G = cadd(a1, a3), K = csub(a1, a3);
    x0 = cadd(E, G); x1 = addpi(F, K); x2 = csub(E, G); x3 = addmi(F, K);
}
__device__ __forceinline__ void bfly_dif1(cpx* z) {
    cpx A = cadd(z[0], z[2]), B = csub(z[0], z[2]), C = cadd(z[1], z[3]), D = csub(z[1], z[3]);
    z[0] = cadd(A, C); z[1] = addmi(B, D); z[2] = csub(A, C); z[3] = addpi(B, D);
}
__device__ __forceinline__ void bfly_dit1(cpx* z) {
    cpx E = cadd(z[0], z[2]), F = csub(z[0], z[2]), G = cadd(z[1], z[3]), K = csub(z[1], z[3]);
    z[0] = cadd(E, G); z[1] = addpi(F, K); z[2] = csub(E, G); z[3] = addmi(F, K);
}
// Hermitian split + product (componentwise in SoA!)
__device__ __forceinline__ void pw(cpx& Zm, cpx& Zr) {
    f2 h = bc(0.5f);
    cpx X{h * (Zm.re + Zr.re), h * (Zm.im - Zr.im)};
    cpx H{h * (Zm.im + Zr.im), h * (Zr.re - Zm.re)};
    cpx Y = cmul(X, H);
    Zm = Y; Zr = {Y.re, -Y.im};
}

// cos/sin of 2*pi*j/16
#define CT1 0.92387953251128674f
#define CT2 0.70710678118654752f
#define CT3 0.38268343236508977f
#define ST1 0.38268343236508977f
#define ST2 0.70710678118654752f
#define ST3 0.92387953251128674f

// ---- first forward double-stage (q=4096,1024) fused with global load ----
__device__ __forceinline__ void fwd_first(float* lds, int tid,
                                          const float* __restrict__ xr,
                                          const float* __restrict__ hr) {
    const cpx ladf[4] = {{bc(1.f), bc(0.f)}, {bc(CT1), bc(-ST1)},
                         {bc(CT2), bc(-ST2)}, {bc(CT3), bc(-ST3)}};
    cpx r[4][4];
    float sn, cs;
    __sincosf(-6.283185307179586f / 16384.f * (float)tid, &sn, &cs);
    // half1 twiddle = half0 * e^{-i*pi/16}
    const float KAc = 0.98078528040323044913f, KAs = -0.19509032201612826785f;
    float csb = cs * KAc - sn * KAs, snb = cs * KAs + sn * KAc;
    cpx u1{mk2(cs, csb), mk2(sn, snb)};
#pragma unroll
    for (int jB = 0; jB < 4; ++jB) {
        const int t = tid + jB * 1024;
        cpx z0{mk2(xr[t], xr[t + 512]), mk2(hr[t], hr[t + 512])};
        cpx z1{mk2(xr[t + 4096], xr[t + 4608]), mk2(hr[t + 4096], hr[t + 4608])};
        cpx w1 = (jB == 0) ? u1 : cmul(u1, ladf[jB]);
        cpx w2 = cmul(w1, w1), w3 = cmul(w2, w1);
        r[0][jB] = cadd(z0, z1);
        r[1][jB] = cmul(addmi(z0, z1), w1);
        r[2][jB] = cmul(csub(z0, z1), w2);
        r[3][jB] = cmul(addpi(z0, z1), w3);
    }
    __sincosf(-6.283185307179586f / 4096.f * (float)tid, &sn, &cs);
    const float KBc = 0.70710678118654752f, KBs = -0.70710678118654752f;  // e^{-i*pi/4}
    float csb2 = cs * KBc - sn * KBs, snb2 = cs * KBs + sn * KBc;
    cpx v1{mk2(cs, csb2), mk2(sn, snb2)};
    cpx v2 = cmul(v1, v1), v3 = cmul(v2, v1);
#pragma unroll
    for (int jA = 0; jA < 4; ++jA)
        bfly_dif(r[jA][0], r[jA][1], r[jA][2], r[jA][3], v1, v2, v3);
    const int wb = wrd(tid);
#pragma unroll
    for (int jA = 0; jA < 4; ++jA)
#pragma unroll
        for (int jB = 0; jB < 4; ++jB) {
            const int wA = wb ^ wrd(jA * 4096 + jB * 1024);
            ldsst(lds, wA, wA ^ 1040, r[jA][jB]);   // 1040 = wrd(512)
        }
}

// ---- fused forward DIF pair: q=QA then q=QA/4 (QA in {256,16}) ----
template<int QA>
__device__ __forceinline__ void fwd_pair(float* lds, int tid) {
    constexpr int QB = QA / 4;
    const cpx ladf[4] = {{bc(1.f), bc(0.f)}, {bc(CT1), bc(-ST1)},
                         {bc(CT2), bc(-ST2)}, {bc(CT3), bc(-ST3)}};
    const int g = tid / QB, u = tid % QB;
    const int wb = wrd(g * (4 * QA) + u);
    cpx r[4][4];
#pragma unroll
    for (int jA = 0; jA < 4; ++jA)
#pragma unroll
        for (int jB = 0; jB < 4; ++jB) {
            const int wA = wb ^ wrd(jA * QA + jB * QB);
            r[jA][jB] = ldsld(lds, wA, wA ^ 16392);   // 16392 = wrd(8192)
        }
    float sn, cs;
    __sincosf(-6.283185307179586f / (float)(4 * QA) * (float)u, &sn, &cs);
    cpx u1{bc(cs), bc(sn)};   // same twiddle for both halves (u == u+512 mod QB)
#pragma unroll
    for (int jB = 0; jB < 4; ++jB) {
        cpx w1 = (jB == 0) ? u1 : cmul(u1, ladf[jB]);
        cpx w2 = cmul(w1, w1), w3 = cmul(w2, w1);
        bfly_dif(r[0][jB], r[1][jB], r[2][jB], r[3][jB], w1, w2, w3);
    }
    __sincosf(-6.283185307179586f / (float)(4 * QB) * (float)u, &sn, &cs);
    cpx v1{bc(cs), bc(sn)}, v2 = cmul(v1, v1), v3 = cmul(v2, v1);
#pragma unroll
    for (int jA = 0; jA < 4; ++jA)
        bfly_dif(r[jA][0], r[jA][1], r[jA][2], r[jA][3], v1, v2, v3);
#pragma unroll
    for (int jA = 0; jA < 4; ++jA)
#pragma unroll
        for (int jB = 0; jB < 4; ++jB) {
            const int wA = wb ^ wrd(jA * QA + jB * QB);
            ldsst(lds, wA, wA ^ 16392, r[jA][jB]);
        }
}

// ---- fused inverse DIT pair: q=QA then q=4*QA (QA in {4,64}) ----
template<int QA>
__device__ __forceinline__ void inv_pair(float* lds, int tid) {
    constexpr int QB = 4 * QA;
    const cpx ladi[4] = {{bc(1.f), bc(0.f)}, {bc(CT1), bc(ST1)},
                         {bc(CT2), bc(ST2)}, {bc(CT3), bc(ST3)}};
    const int G = tid / QA, u = tid % QA;
    const int wb = wrd(G * (16 * QA) + u);
    cpx r[4][4];
#pragma unroll
    for (int jA = 0; jA < 4; ++jA)
#pragma unroll
        for (int jB = 0; jB < 4; ++jB) {
            const int wA = wb ^ wrd(jA * QA + jB * QB);
            r[jA][jB] = ldsld(lds, wA, wA ^ 16392);
        }
    float sn, cs;
    __sincosf(6.283185307179586f / (float)(4 * QA) * (float)u, &sn, &cs);
    cpx a1{bc(cs), bc(sn)}, a2 = cmul(a1, a1), a3 = cmul(a2, a1);
#pragma unroll
    for (int jB = 0; jB < 4; ++jB)
        bfly_dit(r[0][jB], r[1][jB], r[2][jB], r[3][jB], a1, a2, a3);
    __sincosf(6.283185307179586f / (float)(4 * QB) * (float)u, &sn, &cs);
    cpx b1{bc(cs), bc(sn)};
#pragma unroll
    for (int jA = 0; jA < 4; ++jA) {
        cpx w1 = (jA == 0) ? b1 : cmul(b1, ladi[jA]);
        cpx w2 = cmul(w1, w1), w3 = cmul(w2, w1);
        bfly_dit(r[jA][0], r[jA][1], r[jA][2], r[jA][3], w1, w2, w3);
    }
#pragma unroll
    for (int jA = 0; jA < 4; ++jA)
#pragma unroll
        for (int jB = 0; jB < 4; ++jB) {
            const int wA = wb ^ wrd(jA * QA + jB * QB);
            ldsst(lds, wA, wA ^ 16392, r[jA][jB]);
        }
}

// ---- last inverse double-stage (q=1024,4096) fused with global store ----
__device__ __forceinline__ void inv_last(const float* lds, int tid,
                                         float* __restrict__ orow) {
    const cpx ladi[4] = {{bc(1.f), bc(0.f)}, {bc(CT1), bc(ST1)},
                         {bc(CT2), bc(ST2)}, {bc(CT3), bc(ST3)}};
    const int wb = wrd(tid);
    cpx r[4][4];
#pragma unroll
    for (int jA = 0; jA < 4; ++jA)
#pragma unroll
        for (int jB = 0; jB < 4; ++jB) {
            const int wA = wb ^ wrd(jA * 1024 + jB * 4096);
            r[jA][jB] = ldsld(lds, wA, wA ^ 1040);
        }
    float sn, cs;
    __sincosf(6.283185307179586f / 4096.f * (float)tid, &sn, &cs);
    const float PC4 = 0.70710678118654752f, PS4 = 0.70710678118654752f;   // e^{+i*pi/4}
    float csb = cs * PC4 - sn * PS4, snb = cs * PS4 + sn * PC4;
    cpx a1{mk2(cs, csb), mk2(sn, snb)}, a2 = cmul(a1, a1), a3 = cmul(a2, a1);
#pragma unroll
    for (int jB = 0; jB < 4; ++jB)
        bfly_dit(r[0][jB], r[1][jB], r[2][jB], r[3][jB], a1, a2, a3);
    __sincosf(6.283185307179586f / 16384.f * (float)tid, &sn, &cs);
    const float PC16 = 0.98078528040323044913f, PS16 = 0.19509032201612826785f; // e^{+i*pi/16}
    float csb2 = cs * PC16 - sn * PS16, snb2 = cs * PS16 + sn * PC16;
    cpx b1{mk2(cs, csb2), mk2(sn, snb2)};
    const f2 sc = bc(1.0f / (16384.f * 16384.f));   // 2^-28
#pragma unroll
    for (int jA = 0; jA < 4; ++jA) {
        cpx w1 = (jA == 0) ? b1 : cmul(b1, ladi[jA]);
        cpx w2 = cmul(w1, w1), w3 = cmul(w2, w1);
        cpx x0 = r[jA][0];
        cpx A1 = cmul(r[jA][1], w1);
        f2  A2re = r[jA][2].re * w2.re - r[jA][2].im * w2.im;  // only re needed
        cpx A3 = cmul(r[jA][3], w3);
        f2 y0 = (x0.re + A2re + A1.re + A3.re) * sc;   // n = t
        f2 y1 = (x0.re - A2re - A1.im + A3.im) * sc;   // n = t + 4096
        orow[tid + jA * 1024]              = y0.x;
        orow[tid + 512 + jA * 1024]        = y0.y;
        orow[tid + jA * 1024 + 4096]       = y1.x;
        orow[tid + 512 + jA * 1024 + 4096] = y1.y;
    }
}

// ---- combo: fwd q=1 + Hermitian pointwise + inv q=1 ----
__device__ __forceinline__ void combo_pair(float* lds, int p0, int p1) {
    const int wA0 = wrd(4 * rev4_12(p0)), wA1 = wrd(4 * rev4_12(p1));
    const int wB0 = wrd(4 * rev4_12(4096 - p0)), wB1 = wrd(4 * rev4_12(4096 - p1));
    cpx A[4], B[4];
#pragma unroll
    for (int k = 0; k < 4; ++k) {
        A[k] = ldsld(lds, wA0 ^ k, wA1 ^ k);
        B[k] = ldsld(lds, wB0 ^ k, wB1 ^ k);
    }
    bfly_dif1(A); bfly_dif1(B);
    pw(A[0], B[3]); pw(A[1], B[2]); pw(A[2], B[1]); pw(A[3], B[0]);
    bfly_dit1(A); bfly_dit1(B);
#pragma unroll
    for (int k = 0; k < 4; ++k) {
        ldsst(lds, wA0 ^ k, wA1 ^ k, A[k]);
        ldsst(lds, wB0 ^ k, wB1 ^ k, B[k]);
    }
}

// scalar complex for the thread-0 special path
struct c1 { float re, im; };
__device__ __forceinline__ c1 ld1(const float* lds, int w) { return {lds[w], lds[w ^ 32]}; }
__device__ __forceinline__ void st1(float* lds, int w, c1 v) { lds[w] = v.re; lds[w ^ 32] = v.im; }
__device__ __forceinline__ void s_dif1(c1* z) {
    float Ar = z[0].re + z[2].re, Ai = z[0].im + z[2].im;
    float Br = z[0].re - z[2].re, Bi = z[0].im - z[2].im;
    float Cr = z[1].re + z[3].re, Ci = z[1].im + z[3].im;
    float Dr = z[1].re - z[3].re, Di = z[1].im - z[3].im;
    z[0] = {Ar + Cr, Ai + Ci}; z[1] = {Br + Di, Bi - Dr};
    z[2] = {Ar - Cr, Ai - Ci}; z[3] = {Br - Di, Bi + Dr};
}
__device__ __forceinline__ void s_dit1(c1* z) {
    float Er = z[0].re + z[2].re, Ei = z[0].im + z[2].im;
    float Fr = z[0].re - z[2].re, Fi = z[0].im - z[2].im;
    float Gr = z[1].re + z[3].re, Gi = z[1].im + z[3].im;
    float Kr = z[1].re - z[3].re, Ki = z[1].im - z[3].im;
    z[0] = {Er + Gr, Ei + Gi}; z[1] = {Fr - Ki, Fi + Kr};
    z[2] = {Er - Gr, Ei - Gi}; z[3] = {Fr + Ki, Fi - Kr};
}
__device__ __forceinline__ void s_pw(c1& a, c1& b) {
    float Xr = 0.5f * (a.re + b.re), Xi = 0.5f * (a.im - b.im);
    float Hr = 0.5f * (a.im + b.im), Hi = 0.5f * (b.re - a.re);
    float Yr = Xr * Hr - Xi * Hi, Yi = Xr * Hi + Xi * Hr;
    a = {Yr, Yi}; b = {Yr, -Yi};
}
__device__ void combo_special(float* lds) {
    // quad a=0 (words 0..3): bins {0,4096,8192,12288}
    c1 z[4];
#pragma unroll
    for (int k = 0; k < 4; ++k) z[k] = ld1(lds, k);
    s_dif1(z);
    z[0] = {z[0].re * z[0].im, 0.f};   // bin 0
    z[2] = {z[2].re * z[2].im, 0.f};   // bin N/2
    s_pw(z[1], z[3]);                  // 4096 <-> 12288
    s_dit1(z);
#pragma unroll
    for (int k = 0; k < 4; ++k) st1(lds, k, z[k]);
    // quad a=2 (elems 8..11): bins k*4096+2048; internal pairs (0,3),(1,2)
    c1 w[4];
#pragma unroll
    for (int k = 0; k < 4; ++k) w[k] = ld1(lds, 8 + k);
    s_dif1(w);
    s_pw(w[0], w[3]); s_pw(w[1], w[2]);
    s_dit1(w);
#pragma unroll
    for (int k = 0; k < 4; ++k) st1(lds, 8 + k, w[k]);
    // p = 512 (the half-1 partner of thread 0's pair), generic scalar
    const int wA = wrd(4 * rev4_12(512)), wB = wrd(4 * rev4_12(3584));
    c1 A[4], Bq[4];
#pragma unroll
    for (int k = 0; k < 4; ++k) { A[k] = ld1(lds, wA ^ k); Bq[k] = ld1(lds, wB ^ k); }
    s_dif1(A); s_dif1(Bq);
    s_pw(A[0], Bq[3]); s_pw(A[1], Bq[2]); s_pw(A[2], Bq[1]); s_pw(A[3], Bq[0]);
    s_dit1(A); s_dit1(Bq);
#pragma unroll
    for (int k = 0; k < 4; ++k) { st1(lds, wA ^ k, A[k]); st1(lds, wB ^ k, Bq[k]); }
}

__global__ LB
void fftconv_kernel(const float* __restrict__ xin,
                    const float* __restrict__ hin,
                    float* __restrict__ out)
{
    __shared__ float lds[2 * N_FFT];   // 128 KiB: SoA re/im planes in 256B blocks

    const int row = blockIdx.x;
    const int tid = threadIdx.x;
    const float* xr = xin + (size_t)row * L_LEN;
    const float* hr = hin + (size_t)row * L_LEN;

    // ---- forward: fused global-load + q=4096&1024; then 256&64, 16&4 ----
    fwd_first(lds, tid, xr, hr); __syncthreads();
    fwd_pair<256>(lds, tid);     __syncthreads();
    fwd_pair<16>(lds, tid);      __syncthreads();

    // ---- combo: quads b=p pair with b=4096-p; iter0 covers p in [0,1024),
    // iter1 covers [1024,2048); disjoint quad sets -> no barrier between.
    if (tid == 0) combo_special(lds);                 // b=0, b=2048, p=512
    else          combo_pair(lds, tid, tid + 512);
    combo_pair(lds, tid + 1024, tid + 1536);
    __syncthreads();

    // ---- inverse: q=4&16, 64&256; then fused q=1024&4096 + store ----
    inv_pair<4>(lds, tid);  __syncthreads();
    inv_pair<64>(lds, tid); __syncthreads();
    inv_last(lds, tid, out + (size_t)row * L_LEN);
}

extern "C" void kernel_launch(void* const* d_in, const int* in_sizes, int n_in,
                              void* d_out, int out_size, void* d_ws, size_t ws_size,
                              hipStream_t stream) {
    const float* x = (const float*)d_in[0];
    const float* h = (const float*)d_in[1];
    float* out = (float*)d_out;
    const int rows = in_sizes[0] / L_LEN;   // 2048
    fftconv_kernel<<<dim3(rows), dim3(NB), 0, stream>>>(x, h, out);
}

// Round 11
// 129.830 us; speedup vs baseline: 1.0623x; 1.0623x over previous
//
#include <hip/hip_runtime.h>

#define L_LEN 8192
#define N_FFT 16384
#define NB    512     // thread packs positions (i, i+8192) as float4 slots

#define LB __launch_bounds__(NB, 2)

typedef float f2 __attribute__((ext_vector_type(2)));
struct cpx { f2 re, im; };    // packed PAIR of complex values (lanes independent)
struct c1  { float re, im; }; // scalar complex

__device__ __forceinline__ f2 bc(float s) { f2 v; v.x = s; v.y = s; return v; }
__device__ __forceinline__ f2 mk2(float a, float b) { f2 v; v.x = a; v.y = b; return v; }

// packed (componentwise -> v_pk_*) complex ops
__device__ __forceinline__ cpx cadd(cpx a, cpx b) { return {a.re + b.re, a.im + b.im}; }
__device__ __forceinline__ cpx csub(cpx a, cpx b) { return {a.re - b.re, a.im - b.im}; }
__device__ __forceinline__ cpx cmul(cpx a, cpx w) {
    return {a.re * w.re - a.im * w.im, a.re * w.im + a.im * w.re};
}
__device__ __forceinline__ cpx addmi(cpx a, cpx b) { return {a.re + b.im, a.im - b.re}; } // a - i b
__device__ __forceinline__ cpx addpi(cpx a, cpx b) { return {a.re - b.im, a.im + b.re}; } // a + i b

// scalar complex ops
__device__ __forceinline__ c1 smul(c1 a, c1 b) {
    return {a.re * b.re - a.im * b.im, a.re * b.im + a.im * b.re};
}

// slot swizzle: GF(2)-linear => sig(base|off) = sig(base)^sig(off) for disjoint fields
__host__ __device__ constexpr int sig(int s) {
    return s ^ ((((s) >> 3) ^ ((s) >> 6) ^ ((s) >> 9) ^ ((s) >> 12)) & 7);
}

// reverse 6 base-4 digits
__device__ __forceinline__ int rev6(int m) {
    int r = 0;
#pragma unroll
    for (int d = 0; d < 6; ++d) { r = (r << 2) | (m & 3); m >>= 2; }
    return r;
}

// packed butterflies
__device__ __forceinline__ void bfly_dif(cpx& x0, cpx& x1, cpx& x2, cpx& x3,
                                         cpx w1, cpx w2, cpx w3) {
    cpx A = cadd(x0, x2), B = csub(x0, x2), C = cadd(x1, x3), D = csub(x1, x3);
    x0 = cadd(A, C);
    x1 = cmul(addmi(B, D), w1);
    x2 = cmul(csub(A, C), w2);
    x3 = cmul(addpi(B, D), w3);
}
__device__ __forceinline__ void bfly_dit(cpx& x0, cpx& x1, cpx& x2, cpx& x3,
                                         cpx w1, cpx w2, cpx w3) {
    cpx a1 = cmul(x1, w1), a2 = cmul(x2, w2), a3 = cmul(x3, w3);
    cpx E = cadd(x0, a2), F = csub(x0, a2), G = cadd(a1, a3), K = csub(a1, a3);
    x0 = cadd(E, G); x1 = addpi(F, K); x2 = csub(E, G); x3 = addmi(F, K);
}

// scalar q=1 butterflies + pointwise (combo pass)
__device__ __forceinline__ void s_dif1(c1* z) {
    float Ar = z[0].re + z[2].re, Ai = z[0].im + z[2].im;
    float Br = z[0].re - z[2].re, Bi = z[0].im - z[2].im;
    float Cr = z[1].re + z[3].re, Ci = z[1].im + z[3].im;
    float Dr = z[1].re - z[3].re, Di = z[1].im - z[3].im;
    z[0] = {Ar + Cr, Ai + Ci}; z[1] = {Br + Di, Bi - Dr};
    z[2] = {Ar - Cr, Ai - Ci}; z[3] = {Br - Di, Bi + Dr};
}
__device__ __forceinline__ void s_dit1(c1* z) {
    float Er = z[0].re + z[2].re, Ei = z[0].im + z[2].im;
    float Fr = z[0].re - z[2].re, Fi = z[0].im - z[2].im;
    float Gr = z[1].re + z[3].re, Gi = z[1].im + z[3].im;
    float Kr = z[1].re - z[3].re, Ki = z[1].im - z[3].im;
    z[0] = {Er + Gr, Ei + Gi}; z[1] = {Fr - Ki, Fi + Kr};
    z[2] = {Er - Gr, Ei - Gi}; z[3] = {Fr + Ki, Fi - Kr};
}
__device__ __forceinline__ void s_pw(c1& a, c1& b) {
    float Xr = 0.5f * (a.re + b.re), Xi = 0.5f * (a.im - b.im);
    float Hr = 0.5f * (a.im + b.im), Hi = 0.5f * (b.re - a.re);
    float Yr = Xr * Hr - Xi * Hi, Yi = Xr * Hi + Xi * Hr;
    a = {Yr, Yi}; b = {Yr, -Yi};
}

// cos/sin of 2*pi*j/16
#define CT1 0.92387953251128674f
#define CT2 0.70710678118654752f
#define CT3 0.38268343236508977f
#define ST1 0.38268343236508977f
#define ST2 0.70710678118654752f
#define ST3 0.92387953251128674f

__device__ __forceinline__ float4 to4(cpx v) {
    return make_float4(v.re.x, v.re.y, v.im.x, v.im.y);
}
__device__ __forceinline__ cpx fr4(float4 v) {
    return { mk2(v.x, v.y), mk2(v.z, v.w) };
}

// ---- combo helpers: scalar lane access into float4 slots ----
__device__ __forceinline__ c1 ldq(const float* w, int wb, int k, int lane) {
    const int b = wb ^ (4 * k);
    return { w[b + lane], w[b + 2 + lane] };
}
__device__ __forceinline__ void stq(float* w, int wb, int k, int lane, c1 v) {
    const int b = wb ^ (4 * k);
    w[b + lane] = v.re; w[b + 2 + lane] = v.im;
}
__device__ __forceinline__ void quad_pair(float* w, int wbA, int laneA, int wbB, int laneB) {
    c1 A[4], B[4];
#pragma unroll
    for (int k = 0; k < 4; ++k) { A[k] = ldq(w, wbA, k, laneA); B[k] = ldq(w, wbB, k, laneB); }
    s_dif1(A); s_dif1(B);
    s_pw(A[0], B[3]); s_pw(A[1], B[2]); s_pw(A[2], B[1]); s_pw(A[3], B[0]);
    s_dit1(A); s_dit1(B);
#pragma unroll
    for (int k = 0; k < 4; ++k) { stq(w, wbA, k, laneA, A[k]); stq(w, wbB, k, laneB, B[k]); }
}

// ---- fused forward DIF pair on slots: stage q=QA then q=QA/4 ----
template<int QA>
__device__ __forceinline__ void fwd_pair(float4* lds4, int tid) {
    constexpr int QB = QA / 4;
    const int g = tid / QB, u = tid % QB;
    const int sb = sig(g * (4 * QA) + u);
    cpx r[4][4];
#pragma unroll
    for (int jA = 0; jA < 4; ++jA)
#pragma unroll
        for (int jB = 0; jB < 4; ++jB)
            r[jA][jB] = fr4(lds4[sb ^ sig(jA * QA + jB * QB)]);

    const cpx lad[4] = {{bc(1.f), bc(0.f)}, {bc(CT1), bc(-ST1)},
                        {bc(CT2), bc(-ST2)}, {bc(CT3), bc(-ST3)}};
    float sn, cs;
    __sincosf(-6.283185307179586f / (float)(4 * QA) * (float)u, &sn, &cs);
    cpx u1{bc(cs), bc(sn)};
#pragma unroll
    for (int jB = 0; jB < 4; ++jB) {
        cpx w1 = (jB == 0) ? u1 : cmul(u1, lad[jB]);
        cpx w2 = cmul(w1, w1), w3 = cmul(w2, w1);
        bfly_dif(r[0][jB], r[1][jB], r[2][jB], r[3][jB], w1, w2, w3);
    }
    __sincosf(-6.283185307179586f / (float)(4 * QB) * (float)u, &sn, &cs);
    cpx v1{bc(cs), bc(sn)}, v2 = cmul(v1, v1), v3 = cmul(v2, v1);
#pragma unroll
    for (int jA = 0; jA < 4; ++jA)
        bfly_dif(r[jA][0], r[jA][1], r[jA][2], r[jA][3], v1, v2, v3);

#pragma unroll
    for (int jA = 0; jA < 4; ++jA)
#pragma unroll
        for (int jB = 0; jB < 4; ++jB)
            lds4[sb ^ sig(jA * QA + jB * QB)] = to4(r[jA][jB]);
}

// ---- fused inverse DIT pair on slots: stage q=QA then q=4*QA ----
template<int QA>
__device__ __forceinline__ void inv_pair(float4* lds4, int tid) {
    constexpr int QB = 4 * QA;
    const int G = tid / QA, u = tid % QA;
    const int sb = sig(G * (16 * QA) + u);
    cpx r[4][4];
#pragma unroll
    for (int jA = 0; jA < 4; ++jA)
#pragma unroll
        for (int jB = 0; jB < 4; ++jB)
            r[jA][jB] = fr4(lds4[sb ^ sig(jA * QA + jB * QB)]);

    const cpx lad[4] = {{bc(1.f), bc(0.f)}, {bc(CT1), bc(ST1)},
                        {bc(CT2), bc(ST2)}, {bc(CT3), bc(ST3)}};
    float sn, cs;
    __sincosf(6.283185307179586f / (float)(4 * QA) * (float)u, &sn, &cs);
    cpx a1{bc(cs), bc(sn)}, a2 = cmul(a1, a1), a3 = cmul(a2, a1);
#pragma unroll
    for (int jB = 0; jB < 4; ++jB)
        bfly_dit(r[0][jB], r[1][jB], r[2][jB], r[3][jB], a1, a2, a3);
    __sincosf(6.283185307179586f / (float)(4 * QB) * (float)u, &sn, &cs);
    cpx b1{bc(cs), bc(sn)};
#pragma unroll
    for (int jA = 0; jA < 4; ++jA) {
        cpx w1 = (jA == 0) ? b1 : cmul(b1, lad[jA]);
        cpx w2 = cmul(w1, w1), w3 = cmul(w2, w1);
        bfly_dit(r[jA][0], r[jA][1], r[jA][2], r[jA][3], w1, w2, w3);
    }
#pragma unroll
    for (int jA = 0; jA < 4; ++jA)
#pragma unroll
        for (int jB = 0; jB < 4; ++jB)
            lds4[sb ^ sig(jA * QA + jB * QB)] = to4(r[jA][jB]);
}

__global__ LB
void fftconv_kernel(const float* __restrict__ xin,
                    const float* __restrict__ hin,
                    float* __restrict__ out)
{
    __shared__ float4 lds4[L_LEN];   // 8192 slots x 16B = 128 KiB
    float* ldsw = (float*)lds4;

    const int row = blockIdx.x;
    const int tid = threadIdx.x;
    const float* xr = xin + (size_t)row * L_LEN;
    const float* hr = hin + (size_t)row * L_LEN;

    // ---- fwd_first: global load + stage q=4096 (scalar, crosses pack lanes,
    //      upper input half zero) + pack (i,i+8192) + stage q=1024 (packed) ----
    {
        const c1 lads[4] = {{1.f, 0.f}, {CT1, -ST1}, {CT2, -ST2}, {CT3, -ST3}};
#pragma unroll
        for (int h = 0; h < 2; ++h) {
            const int t = tid + 512 * h;
            float sn, cs;
            __sincosf(-6.283185307179586f / 16384.f * (float)t, &sn, &cs);
            c1 u1{cs, sn};
            c1 y0[4], y1[4], y2[4], y3[4];
#pragma unroll
            for (int jB = 0; jB < 4; ++jB) {
                const int p = t + jB * 1024;
                c1 z0{xr[p], hr[p]}, z1{xr[p + 4096], hr[p + 4096]};
                c1 w1 = (jB == 0) ? u1 : smul(u1, lads[jB]);
                c1 w2 = smul(w1, w1), w3 = smul(w2, w1);
                y0[jB] = {z0.re + z1.re, z0.im + z1.im};
                y1[jB] = smul({z0.re + z1.im, z0.im - z1.re}, w1);   // (z0 - i z1) w1
                y2[jB] = smul({z0.re - z1.re, z0.im - z1.im}, w2);
                y3[jB] = smul({z0.re - z1.im, z0.im + z1.re}, w3);   // (z0 + i z1) w3
            }
            // pack: slot p=(y0,y2); slot p+4096=(y1,y3); stage q=1024 packed
            cpx sA[4], sB[4];
#pragma unroll
            for (int jB = 0; jB < 4; ++jB) {
                sA[jB] = { mk2(y0[jB].re, y2[jB].re), mk2(y0[jB].im, y2[jB].im) };
                sB[jB] = { mk2(y1[jB].re, y3[jB].re), mk2(y1[jB].im, y3[jB].im) };
            }
            __sincosf(-6.283185307179586f / 4096.f * (float)t, &sn, &cs);
            cpx v1{bc(cs), bc(sn)}, v2 = cmul(v1, v1), v3 = cmul(v2, v1);
            bfly_dif(sA[0], sA[1], sA[2], sA[3], v1, v2, v3);
            bfly_dif(sB[0], sB[1], sB[2], sB[3], v1, v2, v3);
            const int st4 = sig(t);
#pragma unroll
            for (int jB = 0; jB < 4; ++jB) {
                lds4[st4 ^ sig(jB * 1024)]        = to4(sA[jB]);
                lds4[st4 ^ sig(jB * 1024 + 4096)] = to4(sB[jB]);
            }
        }
    }
    __syncthreads();

    // ---- forward middle: stages (256,64), (16,4) on slot space ----
    fwd_pair<256>(lds4, tid); __syncthreads();
    fwd_pair<16>(lds4, tid);  __syncthreads();

    // ---- combo: fwd q=1 + Hermitian pointwise + inv q=1 ----
    // bins mod 4: lane0 holds {0,1}, lane1 {2,3}. Pairs: 0<->0 (lane0),
    // 2<->2 (lane1), 1<->3 (cross). 4 quad-pairs per thread, disjoint targets.
    {
        float* w = ldsw;
        // class 3 (cross-lane), e and e+512
#pragma unroll
        for (int it = 0; it < 2; ++it) {
            const int e = tid + it * 512;
            const int aL = rev6(4 * e + 1);                 // lane0 quad in [1024,2048)
            const int sH = rev6(4 * (1023 - e) + 3) - 2048; // lane1 slot-quad in [1024,2048)
            quad_pair(w, 4 * sig(4 * aL), 0, 4 * sig(4 * sH), 1);
        }
        // class 2 (lane1-lane1): e <-> 1023-e
        {
            const int e = tid;
            const int qa = rev6(4 * e + 2) - 2048;
            const int qb = rev6(4 * (1023 - e) + 2) - 2048;
            quad_pair(w, 4 * sig(4 * qa), 1, 4 * sig(4 * qb), 1);
        }
        // class 1 (lane0-lane0): e <-> 1024-e; thread 0 does the specials
        if (tid != 0) {
            const int e = tid;
            const int qa = rev6(4 * e);
            const int qb = rev6(4 * (1024 - e));
            quad_pair(w, 4 * sig(4 * qa), 0, 4 * sig(4 * qb), 0);
        } else {
            // quad b=0 (slot-quad 0, lane0): bins {0,4096,8192,12288}
            c1 z[4];
#pragma unroll
            for (int k = 0; k < 4; ++k) z[k] = ldq(w, 0, k, 0);
            s_dif1(z);
            z[0] = {z[0].re * z[0].im, 0.f};
            z[2] = {z[2].re * z[2].im, 0.f};
            s_pw(z[1], z[3]);
            s_dit1(z);
#pragma unroll
            for (int k = 0; k < 4; ++k) stq(w, 0, k, 0, z[k]);
            // quad b=2048 (slot-quad 2, lane0): self-paired entries (0,3),(1,2)
            const int wb2 = 4 * sig(8);
            c1 v[4];
#pragma unroll
            for (int k = 0; k < 4; ++k) v[k] = ldq(w, wb2, k, 0);
            s_dif1(v);
            s_pw(v[0], v[3]); s_pw(v[1], v[2]);
            s_dit1(v);
#pragma unroll
            for (int k = 0; k < 4; ++k) stq(w, wb2, k, 0, v[k]);
        }
    }
    __syncthreads();

    // ---- inverse middle: stages (4,16), (64,256) ----
    inv_pair<4>(lds4, tid);  __syncthreads();
    inv_pair<64>(lds4, tid); __syncthreads();

    // ---- inv_last: stage q=1024 (packed) + unpack + stage q=4096 (scalar,
    //      real parts of outputs < 8192 only) + global store ----
    {
        const c1 lads[4] = {{1.f, 0.f}, {CT1, ST1}, {CT2, ST2}, {CT3, ST3}};
        const float scale = 1.0f / (16384.f * 16384.f);   // 2^-28
        float* orow = out + (size_t)row * L_LEN;
#pragma unroll
        for (int h = 0; h < 2; ++h) {
            const int t = tid + 512 * h;
            const int st4 = sig(t);
            cpx rA[4], rB[4];
#pragma unroll
            for (int jA = 0; jA < 4; ++jA) {
                rA[jA] = fr4(lds4[st4 ^ sig(jA * 1024)]);
                rB[jA] = fr4(lds4[st4 ^ sig(jA * 1024 + 4096)]);
            }
            float sn, cs;
            __sincosf(6.283185307179586f / 4096.f * (float)t, &sn, &cs);
            cpx a1{bc(cs), bc(sn)}, a2 = cmul(a1, a1), a3 = cmul(a2, a1);
            bfly_dit(rA[0], rA[1], rA[2], rA[3], a1, a2, a3);
            bfly_dit(rB[0], rB[1], rB[2], rB[3], a1, a2, a3);

            __sincosf(6.283185307179586f / 16384.f * (float)t, &sn, &cs);
            c1 b1{cs, sn};
#pragma unroll
            for (int jA = 0; jA < 4; ++jA) {
                c1 w1 = (jA == 0) ? b1 : smul(b1, lads[jA]);
                c1 w2 = smul(w1, w1), w3 = smul(w2, w1);
                // unpack: positions p, p+4096, p+8192, p+12288
                c1 x0{rA[jA].re.x, rA[jA].im.x};
                c1 x1{rB[jA].re.x, rB[jA].im.x};
                c1 x2{rA[jA].re.y, rA[jA].im.y};
                c1 x3{rB[jA].re.y, rB[jA].im.y};
                c1 A1 = smul(x1, w1), A3 = smul(x3, w3);
                float A2re = x2.re * w2.re - x2.im * w2.im;
                float y0 = x0.re + A2re + A1.re + A3.re;
                float y1 = x0.re - A2re - A1.im + A3.im;
                orow[t + jA * 1024]        = y0 * scale;
                orow[t + jA * 1024 + 4096] = y1 * scale;
            }
        }
    }
}

extern "C" void kernel_launch(void* const* d_in, const int* in_sizes, int n_in,
                              void* d_out, int out_size, void* d_ws, size_t ws_size,
                              hipStream_t stream) {
    const float* x = (const float*)d_in[0];
    const float* h = (const float*)d_in[1];
    float* out = (float*)d_out;
    const int rows = in_sizes[0] / L_LEN;   // 2048
    fftconv_kernel<<<dim3(rows), dim3(NB), 0, stream>>>(x, h, out);
}

// Round 12
// 112.749 us; speedup vs baseline: 1.2232x; 1.1515x over previous
//
#include <hip/hip_runtime.h>

#define L_LEN 8192
#define N_FFT 16384   // 2*L
#define NB    1024    // threads per block; each thread owns 16 points per pass

#define LB __launch_bounds__(NB)

// 2-wide float vector = one complex value (re, im).
typedef float f2 __attribute__((ext_vector_type(2)));

__device__ __forceinline__ f2 mkf2(float a, float b) { f2 v; v.x = a; v.y = b; return v; }

__device__ __forceinline__ f2 cmul(f2 a, f2 w) {
    return mkf2(a.y, a.y) * mkf2(-w.y, w.x) + mkf2(a.x, a.x) * w;
}

// bijective LDS index swizzle: GF(2)-linear, so with disjoint bit fields
// swz(base+off) = swz(base) ^ swz(off) and swz(off) constant-folds.
// Only bits 0-3 change => 1024-point group membership is preserved
// (wave-locality of the middle passes survives the swizzle).
__host__ __device__ constexpr int swz(int i) {
    return i ^ ((((i) >> 4) ^ ((i) >> 8) ^ ((i) >> 12)) & 15);
}

// reverse 6 base-4 digits
__device__ __forceinline__ int rev4_12(int m) {
    int r = 0;
#pragma unroll
    for (int d = 0; d < 6; ++d) { r = (r << 2) | (m & 3); m >>= 2; }
    return r;
}

// DIF radix-4 butterfly, twiddles (w1,w2,w3) precomputed by caller.
__device__ __forceinline__ void bfly_dif(f2& x0, f2& x1, f2& x2, f2& x3,
                                         f2 w1, f2 w2, f2 w3) {
    f2 A = x0 + x2, B = x0 - x2, C = x1 + x3, D = x1 - x3;
    f2 iD = mkf2(-D.y, D.x);
    x0 = A + C;
    x1 = cmul(B - iD, w1);
    x2 = cmul(A - C, w2);
    x3 = cmul(B + iD, w3);
}

// DIT radix-4 butterfly: twiddle-multiply inputs then combine.
__device__ __forceinline__ void bfly_dit(f2& x0, f2& x1, f2& x2, f2& x3,
                                         f2 w1, f2 w2, f2 w3) {
    f2 a1 = cmul(x1, w1), a2 = cmul(x2, w2), a3 = cmul(x3, w3);
    f2 E = x0 + a2, F = x0 - a2, G = a1 + a3, K = a1 - a3;
    f2 iK = mkf2(-K.y, K.x);
    x0 = E + G; x1 = F + iK; x2 = E - G; x3 = F - iK;
}

// twiddle-free variants (t=0)
__device__ __forceinline__ void bfly_dif1(f2* z) {
    f2 A = z[0] + z[2], B = z[0] - z[2], C = z[1] + z[3], D = z[1] - z[3];
    f2 iD = mkf2(-D.y, D.x);
    z[0] = A + C; z[1] = B - iD; z[2] = A - C; z[3] = B + iD;
}
__device__ __forceinline__ void bfly_dit1(f2* z) {
    f2 E = z[0] + z[2], F = z[0] - z[2], G = z[1] + z[3], K = z[1] - z[3];
    f2 iK = mkf2(-K.y, K.x);
    z[0] = E + G; z[1] = F + iK; z[2] = E - G; z[3] = F - iK;
}

// pointwise Y = X*H from Z[m], Z[N-m] of the packed z = x + i*h transform
__device__ __forceinline__ void pointwise_pair(f2& Zm, f2& Zr) {
    f2 half = mkf2(0.5f, 0.5f);
    f2 X = half * (Zm + mkf2(Zr.x, -Zr.y));
    f2 H = half * (mkf2(Zm.y, -Zm.x) + mkf2(Zr.y, Zr.x));
    f2 Y = cmul(X, H);
    Zm = Y;
    Zr = mkf2(Y.x, -Y.y);
}

// cos/sin of 2*pi*j/16, j=0..3
#define CT0 1.0f
#define CT1 0.92387953251128674f
#define CT2 0.70710678118654752f
#define CT3 0.38268343236508977f
#define ST1 0.38268343236508977f
#define ST2 0.70710678118654752f
#define ST3 0.92387953251128674f

// First forward double-stage (q=4096 then q=1024), fused with global load.
// Upper half of the zero-padded input is 0: x2=x3=0 in the q=4096 butterfly.
__device__ __forceinline__ void fwd_first(f2* lds, int tid,
                                          const float* __restrict__ xr,
                                          const float* __restrict__ hr) {
    f2 r[4][4];
    const float angA = -6.283185307179586f / 16384.f;
    float snA, csA;
    __sincosf(angA * (float)tid, &snA, &csA);
    f2 u1 = mkf2(csA, snA);
    const f2 lad[4] = {mkf2(CT0, 0.f), mkf2(CT1, -ST1), mkf2(CT2, -ST2), mkf2(CT3, -ST3)};
#pragma unroll
    for (int jB = 0; jB < 4; ++jB) {
        const int t = tid + jB * 1024;
        f2 z0 = mkf2(xr[t], hr[t]);
        f2 z1 = mkf2(xr[t + 4096], hr[t + 4096]);
        f2 w1 = (jB == 0) ? u1 : cmul(u1, lad[jB]);
        f2 w2 = cmul(w1, w1);
        f2 w3 = cmul(w2, w1);
        f2 iz1 = mkf2(-z1.y, z1.x);
        r[0][jB] = z0 + z1;                 // A + C
        r[1][jB] = cmul(z0 - iz1, w1);      // (B - iD) W
        r[2][jB] = cmul(z0 - z1, w2);       // (A - C) W^2
        r[3][jB] = cmul(z0 + iz1, w3);      // (B + iD) W^3
    }
    // stage B (q=1024): same twiddle V^tid for all rows, V = e^{-2pi*i/4096}
    const float angB = -6.283185307179586f / 4096.f;
    float sn, cs;
    __sincosf(angB * (float)tid, &sn, &cs);
    f2 v1 = mkf2(cs, sn);
    f2 v2 = cmul(v1, v1);
    f2 v3 = cmul(v2, v1);
#pragma unroll
    for (int jA = 0; jA < 4; ++jA)
        bfly_dif(r[jA][0], r[jA][1], r[jA][2], r[jA][3], v1, v2, v3);

    const int sb = swz(tid);
#pragma unroll
    for (int jA = 0; jA < 4; ++jA)
#pragma unroll
        for (int jB = 0; jB < 4; ++jB)
            lds[sb ^ swz(jA * 4096 + jB * 1024)] = r[jA][jB];
}

// Last inverse double-stage (q=1024 then q=4096), fused with global store.
// Only outputs n < 8192 are needed, and only their real parts.
__device__ __forceinline__ void inv_last(const f2* lds, int tid,
                                         float* __restrict__ orow) {
    const int sb = swz(tid);
    f2 r[4][4];
#pragma unroll
    for (int jA = 0; jA < 4; ++jA)
#pragma unroll
        for (int jB = 0; jB < 4; ++jB)
            r[jA][jB] = lds[sb ^ swz(jA * 1024 + jB * 4096)];

    // stage A (q=1024): same twiddle for all columns, e^{+2pi*i*tid/4096}
    {
        const float angA = 6.283185307179586f / 4096.f;
        float sn, cs;
        __sincosf(angA * (float)tid, &sn, &cs);
        f2 a1 = mkf2(cs, sn);
        f2 a2 = cmul(a1, a1);
        f2 a3 = cmul(a2, a1);
#pragma unroll
        for (int jB = 0; jB < 4; ++jB)
            bfly_dit(r[0][jB], r[1][jB], r[2][jB], r[3][jB], a1, a2, a3);
    }
    // stage B (q=4096): twiddle w1 = e^{+2pi*i*(tid + jA*1024)/16384};
    // emit real parts of y0 (n = t) and y1 (n = t + 4096) only.
    const float scale = 1.0f / ((float)N_FFT * (float)N_FFT);   // 2^-28
    const float angB = 6.283185307179586f / 16384.f;
    float sn, cs;
    __sincosf(angB * (float)tid, &sn, &cs);
    f2 b1 = mkf2(cs, sn);
    const f2 lad[4] = {mkf2(CT0, 0.f), mkf2(CT1, ST1), mkf2(CT2, ST2), mkf2(CT3, ST3)};
#pragma unroll
    for (int jA = 0; jA < 4; ++jA) {
        f2 w1 = (jA == 0) ? b1 : cmul(b1, lad[jA]);
        f2 w2 = cmul(w1, w1);
        f2 w3 = cmul(w2, w1);
        f2 x0 = r[jA][0];
        f2 a1 = cmul(r[jA][1], w1);
        f2 a2 = cmul(r[jA][2], w2);
        f2 a3 = cmul(r[jA][3], w3);
        // y0 = (x0+a2) + (a1+a3);  y1 = (x0-a2) + i(a1-a3)
        float y0 = x0.x + a2.x + a1.x + a3.x;
        float y1 = x0.x - a2.x - a1.y + a3.y;
        orow[tid + jA * 1024]        = y0 * scale;
        orow[tid + jA * 1024 + 4096] = y1 * scale;
    }
}

// Fused forward DIF pair: stage q=QA then q=QA/4, one LDS round-trip.
template<int QA>
__device__ __forceinline__ void fwd_pair(f2* lds, int tid) {
    constexpr int QB = QA / 4;
    const int g = tid / QB;
    const int u = tid % QB;
    const int sb = swz(g * (4 * QA) + u);
    f2 r[4][4];
#pragma unroll
    for (int jA = 0; jA < 4; ++jA)
#pragma unroll
        for (int jB = 0; jB < 4; ++jB)
            r[jA][jB] = lds[sb ^ swz(jA * QA + jB * QB)];

    {
        const float angA = -6.283185307179586f / (float)(4 * QA);
        float sn, cs;
        __sincosf(angA * (float)u, &sn, &cs);
        f2 u1 = mkf2(cs, sn);
        const f2 lad[4] = {mkf2(CT0, 0.f), mkf2(CT1, -ST1), mkf2(CT2, -ST2), mkf2(CT3, -ST3)};
#pragma unroll
        for (int jB = 0; jB < 4; ++jB) {
            f2 w1 = (jB == 0) ? u1 : cmul(u1, lad[jB]);
            f2 w2 = cmul(w1, w1);
            f2 w3 = cmul(w2, w1);
            bfly_dif(r[0][jB], r[1][jB], r[2][jB], r[3][jB], w1, w2, w3);
        }
    }
    {
        const float angB = -6.283185307179586f / (float)(4 * QB);
        float sn, cs;
        __sincosf(angB * (float)u, &sn, &cs);
        f2 v1 = mkf2(cs, sn);
        f2 v2 = cmul(v1, v1);
        f2 v3 = cmul(v2, v1);
#pragma unroll
        for (int jA = 0; jA < 4; ++jA)
            bfly_dif(r[jA][0], r[jA][1], r[jA][2], r[jA][3], v1, v2, v3);
    }

#pragma unroll
    for (int jA = 0; jA < 4; ++jA)
#pragma unroll
        for (int jB = 0; jB < 4; ++jB)
            lds[sb ^ swz(jA * QA + jB * QB)] = r[jA][jB];
}

// Fused inverse DIT pair: stage q=QA then q=4*QA, one LDS round-trip.
template<int QA>
__device__ __forceinline__ void inv_pair(f2* lds, int tid) {
    constexpr int QB = 4 * QA;
    const int G = tid / QA;
    const int u = tid % QA;
    const int sb = swz(G * (16 * QA) + u);
    f2 r[4][4];
#pragma unroll
    for (int jA = 0; jA < 4; ++jA)
#pragma unroll
        for (int jB = 0; jB < 4; ++jB)
            r[jA][jB] = lds[sb ^ swz(jA * QA + jB * QB)];

    {
        const float angA = 6.283185307179586f / (float)(4 * QA);
        float sn, cs;
        __sincosf(angA * (float)u, &sn, &cs);
        f2 a1 = mkf2(cs, sn);
        f2 a2 = cmul(a1, a1);
        f2 a3 = cmul(a2, a1);
#pragma unroll
        for (int jB = 0; jB < 4; ++jB)
            bfly_dit(r[0][jB], r[1][jB], r[2][jB], r[3][jB], a1, a2, a3);
    }
    {
        const float angB = 6.283185307179586f / (float)(4 * QB);
        float sn, cs;
        __sincosf(angB * (float)u, &sn, &cs);
        f2 b1 = mkf2(cs, sn);
        const f2 lad[4] = {mkf2(CT0, 0.f), mkf2(CT1, ST1), mkf2(CT2, ST2), mkf2(CT3, ST3)};
#pragma unroll
        for (int jA = 0; jA < 4; ++jA) {
            f2 w1 = (jA == 0) ? b1 : cmul(b1, lad[jA]);
            f2 w2 = cmul(w1, w1);
            f2 w3 = cmul(w2, w1);
            bfly_dit(r[jA][0], r[jA][1], r[jA][2], r[jA][3], w1, w2, w3);
        }
    }

#pragma unroll
    for (int jA = 0; jA < 4; ++jA)
#pragma unroll
        for (int jB = 0; jB < 4; ++jB)
            lds[sb ^ swz(jA * QA + jB * QB)] = r[jA][jB];
}

__global__ LB
void fftconv_kernel(const float* __restrict__ xin,
                    const float* __restrict__ hin,
                    float* __restrict__ out)
{
    __shared__ f2 lds[N_FFT];   // 128 KiB

    const int row = blockIdx.x;
    const int tid = threadIdx.x;
    const float* xr = xin + (size_t)row * L_LEN;
    const float* hr = hin + (size_t)row * L_LEN;

    // ---- forward: fused global-load + q=4096&1024 (cross-wave) ----
    fwd_first(lds, tid, xr, hr);
    __syncthreads();

    // ---- fwd q=256&64 then q=16&4: BOTH wave-local to 1024-point group w ----
    // (wave w = tids [64w,64w+64): fp256 has g=tid/64=w; fp16 has
    //  g=tid/4 in [16w,16w+16) -> same [1024w,1024w+1024) range; swz only
    //  permutes bits 0-3 so locality is preserved. Same-wave DS ops are
    //  processed in order by the LDS unit -> no barrier, just a compiler fence.)
    fwd_pair<256>(lds, tid);
    asm volatile("" ::: "memory");
    fwd_pair<16>(lds, tid);
    __syncthreads();

    // ---- combo pass: fwd q=1 + Hermitian pointwise + inv q=1 (cross-wave) ----
#pragma unroll
    for (int iter = 0; iter < 2; ++iter) {
        const int p = tid + iter * NB;          // p in [0, 2048)
        if (p == 0) {
            f2 z[4];
#pragma unroll
            for (int k = 0; k < 4; ++k) z[k] = lds[k];
            bfly_dif1(z);
            z[0] = mkf2(z[0].x * z[0].y, 0.f);   // bin 0
            z[2] = mkf2(z[2].x * z[2].y, 0.f);   // bin N/2
            pointwise_pair(z[1], z[3]);          // 4096 <-> 12288
            bfly_dit1(z);
#pragma unroll
            for (int k = 0; k < 4; ++k) lds[k] = z[k];
            f2 w[4];
#pragma unroll
            for (int k = 0; k < 4; ++k) w[k] = lds[8 + k];
            bfly_dif1(w);
            pointwise_pair(w[0], w[3]);
            pointwise_pair(w[1], w[2]);
            bfly_dit1(w);
#pragma unroll
            for (int k = 0; k < 4; ++k) lds[8 + k] = w[k];
        } else {
            const int sA = swz(4 * rev4_12(p));
            const int sB = swz(4 * rev4_12(4096 - p));
            f2 A[4], B[4];
#pragma unroll
            for (int k = 0; k < 4; ++k) A[k] = lds[sA ^ k];
#pragma unroll
            for (int k = 0; k < 4; ++k) B[k] = lds[sB ^ k];
            bfly_dif1(A);
            bfly_dif1(B);
            pointwise_pair(A[0], B[3]);
            pointwise_pair(A[1], B[2]);
            pointwise_pair(A[2], B[1]);
            pointwise_pair(A[3], B[0]);
            bfly_dit1(A);
            bfly_dit1(B);
#pragma unroll
            for (int k = 0; k < 4; ++k) lds[sA ^ k] = A[k];
#pragma unroll
            for (int k = 0; k < 4; ++k) lds[sB ^ k] = B[k];
        }
    }
    __syncthreads();

    // ---- inv q=4&16 then q=64&256: both wave-local (same group argument) ----
    inv_pair<4>(lds, tid);
    asm volatile("" ::: "memory");
    inv_pair<64>(lds, tid);
    __syncthreads();

    // ---- fused q=1024&4096 + store (cross-wave) ----
    inv_last(lds, tid, out + (size_t)row * L_LEN);
}

extern "C" void kernel_launch(void* const* d_in, const int* in_sizes, int n_in,
                              void* d_out, int out_size, void* d_ws, size_t ws_size,
                              hipStream_t stream) {
    const float* x = (const float*)d_in[0];
    const float* h = (const float*)d_in[1];
    float* out = (float*)d_out;
    const int rows = in_sizes[0] / L_LEN;   // 2048
    fftconv_kernel<<<dim3(rows), dim3(NB), 0, stream>>>(x, h, out);
}

// Round 13
// 112.186 us; speedup vs baseline: 1.2294x; 1.0050x over previous
//
#include <hip/hip_runtime.h>

#define L_LEN 8192
#define N_FFT 16384   // 2*L
#define NB    1024    // threads per block; each thread owns 16 points per pass

#define LB __launch_bounds__(NB)

// 2-wide float vector = one complex value (re, im).
typedef float f2 __attribute__((ext_vector_type(2)));

__device__ __forceinline__ f2 mkf2(float a, float b) { f2 v; v.x = a; v.y = b; return v; }

__device__ __forceinline__ f2 cmul(f2 a, f2 w) {
    return mkf2(a.y, a.y) * mkf2(-w.y, w.x) + mkf2(a.x, a.x) * w;
}

// Native hardware sin/cos taking REVOLUTIONS. Every twiddle angle here is an
// exact dyadic rational (u / 2^k, |rev| <= 1/4): the argument multiply is
// exact and no range reduction is needed — replaces OCML __sincosf entirely.
__device__ __forceinline__ void sincos_rev(float rev, float* sn, float* cs) {
    *sn = __builtin_amdgcn_sinf(rev);
    *cs = __builtin_amdgcn_cosf(rev);
}

// bijective LDS index swizzle: GF(2)-linear, so with disjoint bit fields
// swz(base+off) = swz(base) ^ swz(off) and swz(off) constant-folds.
// Only bits 0-3 change => 1024-point group membership is preserved
// (wave-locality of the middle passes survives the swizzle).
__host__ __device__ constexpr int swz(int i) {
    return i ^ ((((i) >> 4) ^ ((i) >> 8) ^ ((i) >> 12)) & 15);
}

// reverse 6 base-4 digits
__device__ __forceinline__ int rev4_12(int m) {
    int r = 0;
#pragma unroll
    for (int d = 0; d < 6; ++d) { r = (r << 2) | (m & 3); m >>= 2; }
    return r;
}

// DIF radix-4 butterfly, twiddles (w1,w2,w3) precomputed by caller.
__device__ __forceinline__ void bfly_dif(f2& x0, f2& x1, f2& x2, f2& x3,
                                         f2 w1, f2 w2, f2 w3) {
    f2 A = x0 + x2, B = x0 - x2, C = x1 + x3, D = x1 - x3;
    f2 iD = mkf2(-D.y, D.x);
    x0 = A + C;
    x1 = cmul(B - iD, w1);
    x2 = cmul(A - C, w2);
    x3 = cmul(B + iD, w3);
}

// DIT radix-4 butterfly: twiddle-multiply inputs then combine.
__device__ __forceinline__ void bfly_dit(f2& x0, f2& x1, f2& x2, f2& x3,
                                         f2 w1, f2 w2, f2 w3) {
    f2 a1 = cmul(x1, w1), a2 = cmul(x2, w2), a3 = cmul(x3, w3);
    f2 E = x0 + a2, F = x0 - a2, G = a1 + a3, K = a1 - a3;
    f2 iK = mkf2(-K.y, K.x);
    x0 = E + G; x1 = F + iK; x2 = E - G; x3 = F - iK;
}

// twiddle-free variants (t=0)
__device__ __forceinline__ void bfly_dif1(f2* z) {
    f2 A = z[0] + z[2], B = z[0] - z[2], C = z[1] + z[3], D = z[1] - z[3];
    f2 iD = mkf2(-D.y, D.x);
    z[0] = A + C; z[1] = B - iD; z[2] = A - C; z[3] = B + iD;
}
__device__ __forceinline__ void bfly_dit1(f2* z) {
    f2 E = z[0] + z[2], F = z[0] - z[2], G = z[1] + z[3], K = z[1] - z[3];
    f2 iK = mkf2(-K.y, K.x);
    z[0] = E + G; z[1] = F + iK; z[2] = E - G; z[3] = F - iK;
}

// pointwise Y = X*H from Z[m], Z[N-m] of the packed z = x + i*h transform
__device__ __forceinline__ void pointwise_pair(f2& Zm, f2& Zr) {
    f2 half = mkf2(0.5f, 0.5f);
    f2 X = half * (Zm + mkf2(Zr.x, -Zr.y));
    f2 H = half * (mkf2(Zm.y, -Zm.x) + mkf2(Zr.y, Zr.x));
    f2 Y = cmul(X, H);
    Zm = Y;
    Zr = mkf2(Y.x, -Y.y);
}

// cos/sin of 2*pi*j/16, j=0..3
#define CT0 1.0f
#define CT1 0.92387953251128674f
#define CT2 0.70710678118654752f
#define CT3 0.38268343236508977f
#define ST1 0.38268343236508977f
#define ST2 0.70710678118654752f
#define ST3 0.92387953251128674f

// First forward double-stage (q=4096 then q=1024), fused with global load.
// Upper half of the zero-padded input is 0: x2=x3=0 in the q=4096 butterfly.
__device__ __forceinline__ void fwd_first(f2* lds, int tid,
                                          const float* __restrict__ xr,
                                          const float* __restrict__ hr) {
    f2 r[4][4];
    float snA, csA;
    sincos_rev((float)tid * (-1.0f / 16384.f), &snA, &csA);
    f2 u1 = mkf2(csA, snA);
    const f2 lad[4] = {mkf2(CT0, 0.f), mkf2(CT1, -ST1), mkf2(CT2, -ST2), mkf2(CT3, -ST3)};
#pragma unroll
    for (int jB = 0; jB < 4; ++jB) {
        const int t = tid + jB * 1024;
        f2 z0 = mkf2(xr[t], hr[t]);
        f2 z1 = mkf2(xr[t + 4096], hr[t + 4096]);
        f2 w1 = (jB == 0) ? u1 : cmul(u1, lad[jB]);
        f2 w2 = cmul(w1, w1);
        f2 w3 = cmul(w2, w1);
        f2 iz1 = mkf2(-z1.y, z1.x);
        r[0][jB] = z0 + z1;                 // A + C
        r[1][jB] = cmul(z0 - iz1, w1);      // (B - iD) W
        r[2][jB] = cmul(z0 - z1, w2);       // (A - C) W^2
        r[3][jB] = cmul(z0 + iz1, w3);      // (B + iD) W^3
    }
    // stage B (q=1024): same twiddle V^tid for all rows, V = e^{-2pi*i/4096}
    float sn, cs;
    sincos_rev((float)tid * (-1.0f / 4096.f), &sn, &cs);
    f2 v1 = mkf2(cs, sn);
    f2 v2 = cmul(v1, v1);
    f2 v3 = cmul(v2, v1);
#pragma unroll
    for (int jA = 0; jA < 4; ++jA)
        bfly_dif(r[jA][0], r[jA][1], r[jA][2], r[jA][3], v1, v2, v3);

    const int sb = swz(tid);
#pragma unroll
    for (int jA = 0; jA < 4; ++jA)
#pragma unroll
        for (int jB = 0; jB < 4; ++jB)
            lds[sb ^ swz(jA * 4096 + jB * 1024)] = r[jA][jB];
}

// Last inverse double-stage (q=1024 then q=4096), fused with global store.
// Only outputs n < 8192 are needed, and only their real parts.
__device__ __forceinline__ void inv_last(const f2* lds, int tid,
                                         float* __restrict__ orow) {
    const int sb = swz(tid);
    f2 r[4][4];
#pragma unroll
    for (int jA = 0; jA < 4; ++jA)
#pragma unroll
        for (int jB = 0; jB < 4; ++jB)
            r[jA][jB] = lds[sb ^ swz(jA * 1024 + jB * 4096)];

    // stage A (q=1024): same twiddle for all columns, e^{+2pi*i*tid/4096}
    {
        float sn, cs;
        sincos_rev((float)tid * (1.0f / 4096.f), &sn, &cs);
        f2 a1 = mkf2(cs, sn);
        f2 a2 = cmul(a1, a1);
        f2 a3 = cmul(a2, a1);
#pragma unroll
        for (int jB = 0; jB < 4; ++jB)
            bfly_dit(r[0][jB], r[1][jB], r[2][jB], r[3][jB], a1, a2, a3);
    }
    // stage B (q=4096): twiddle w1 = e^{+2pi*i*(tid + jA*1024)/16384};
    // emit real parts of y0 (n = t) and y1 (n = t + 4096) only.
    const float scale = 1.0f / ((float)N_FFT * (float)N_FFT);   // 2^-28
    float sn, cs;
    sincos_rev((float)tid * (1.0f / 16384.f), &sn, &cs);
    f2 b1 = mkf2(cs, sn);
    const f2 lad[4] = {mkf2(CT0, 0.f), mkf2(CT1, ST1), mkf2(CT2, ST2), mkf2(CT3, ST3)};
#pragma unroll
    for (int jA = 0; jA < 4; ++jA) {
        f2 w1 = (jA == 0) ? b1 : cmul(b1, lad[jA]);
        f2 w2 = cmul(w1, w1);
        f2 w3 = cmul(w2, w1);
        f2 x0 = r[jA][0];
        f2 a1 = cmul(r[jA][1], w1);
        f2 a2 = cmul(r[jA][2], w2);
        f2 a3 = cmul(r[jA][3], w3);
        // y0 = (x0+a2) + (a1+a3);  y1 = (x0-a2) + i(a1-a3)
        float y0 = x0.x + a2.x + a1.x + a3.x;
        float y1 = x0.x - a2.x - a1.y + a3.y;
        orow[tid + jA * 1024]        = y0 * scale;
        orow[tid + jA * 1024 + 4096] = y1 * scale;
    }
}

// Fused forward DIF pair: stage q=QA then q=QA/4, one LDS round-trip.
template<int QA>
__device__ __forceinline__ void fwd_pair(f2* lds, int tid) {
    constexpr int QB = QA / 4;
    const int g = tid / QB;
    const int u = tid % QB;
    const int sb = swz(g * (4 * QA) + u);
    f2 r[4][4];
#pragma unroll
    for (int jA = 0; jA < 4; ++jA)
#pragma unroll
        for (int jB = 0; jB < 4; ++jB)
            r[jA][jB] = lds[sb ^ swz(jA * QA + jB * QB)];

    {
        float sn, cs;
        sincos_rev((float)u * (-1.0f / (float)(4 * QA)), &sn, &cs);
        f2 u1 = mkf2(cs, sn);
        const f2 lad[4] = {mkf2(CT0, 0.f), mkf2(CT1, -ST1), mkf2(CT2, -ST2), mkf2(CT3, -ST3)};
#pragma unroll
        for (int jB = 0; jB < 4; ++jB) {
            f2 w1 = (jB == 0) ? u1 : cmul(u1, lad[jB]);
            f2 w2 = cmul(w1, w1);
            f2 w3 = cmul(w2, w1);
            bfly_dif(r[0][jB], r[1][jB], r[2][jB], r[3][jB], w1, w2, w3);
        }
    }
    {
        float sn, cs;
        sincos_rev((float)u * (-1.0f / (float)(4 * QB)), &sn, &cs);
        f2 v1 = mkf2(cs, sn);
        f2 v2 = cmul(v1, v1);
        f2 v3 = cmul(v2, v1);
#pragma unroll
        for (int jA = 0; jA < 4; ++jA)
            bfly_dif(r[jA][0], r[jA][1], r[jA][2], r[jA][3], v1, v2, v3);
    }

#pragma unroll
    for (int jA = 0; jA < 4; ++jA)
#pragma unroll
        for (int jB = 0; jB < 4; ++jB)
            lds[sb ^ swz(jA * QA + jB * QB)] = r[jA][jB];
}

// Fused inverse DIT pair: stage q=QA then q=4*QA, one LDS round-trip.
template<int QA>
__device__ __forceinline__ void inv_pair(f2* lds, int tid) {
    constexpr int QB = 4 * QA;
    const int G = tid / QA;
    const int u = tid % QA;
    const int sb = swz(G * (16 * QA) + u);
    f2 r[4][4];
#pragma unroll
    for (int jA = 0; jA < 4; ++jA)
#pragma unroll
        for (int jB = 0; jB < 4; ++jB)
            r[jA][jB] = lds[sb ^ swz(jA * QA + jB * QB)];

    {
        float sn, cs;
        sincos_rev((float)u * (1.0f / (float)(4 * QA)), &sn, &cs);
        f2 a1 = mkf2(cs, sn);
        f2 a2 = cmul(a1, a1);
        f2 a3 = cmul(a2, a1);
#pragma unroll
        for (int jB = 0; jB < 4; ++jB)
            bfly_dit(r[0][jB], r[1][jB], r[2][jB], r[3][jB], a1, a2, a3);
    }
    {
        float sn, cs;
        sincos_rev((float)u * (1.0f / (float)(4 * QB)), &sn, &cs);
        f2 b1 = mkf2(cs, sn);
        const f2 lad[4] = {mkf2(CT0, 0.f), mkf2(CT1, ST1), mkf2(CT2, ST2), mkf2(CT3, ST3)};
#pragma unroll
        for (int jA = 0; jA < 4; ++jA) {
            f2 w1 = (jA == 0) ? b1 : cmul(b1, lad[jA]);
            f2 w2 = cmul(w1, w1);
            f2 w3 = cmul(w2, w1);
            bfly_dit(r[jA][0], r[jA][1], r[jA][2], r[jA][3], w1, w2, w3);
        }
    }

#pragma unroll
    for (int jA = 0; jA < 4; ++jA)
#pragma unroll
        for (int jB = 0; jB < 4; ++jB)
            lds[sb ^ swz(jA * QA + jB * QB)] = r[jA][jB];
}

__global__ LB
void fftconv_kernel(const float* __restrict__ xin,
                    const float* __restrict__ hin,
                    float* __restrict__ out)
{
    __shared__ f2 lds[N_FFT];   // 128 KiB

    const int row = blockIdx.x;
    const int tid = threadIdx.x;
    const float* xr = xin + (size_t)row * L_LEN;
    const float* hr = hin + (size_t)row * L_LEN;

    // ---- forward: fused global-load + q=4096&1024 (cross-wave) ----
    fwd_first(lds, tid, xr, hr);
    __syncthreads();

    // ---- fwd q=256&64 then q=16&4: both wave-local to 1024-point group w ----
    fwd_pair<256>(lds, tid);
    asm volatile("" ::: "memory");
    fwd_pair<16>(lds, tid);
    __syncthreads();

    // ---- combo pass: fwd q=1 + Hermitian pointwise + inv q=1 (cross-wave) ----
#pragma unroll
    for (int iter = 0; iter < 2; ++iter) {
        const int p = tid + iter * NB;          // p in [0, 2048)
        if (p == 0) {
            f2 z[4];
#pragma unroll
            for (int k = 0; k < 4; ++k) z[k] = lds[k];
            bfly_dif1(z);
            z[0] = mkf2(z[0].x * z[0].y, 0.f);   // bin 0
            z[2] = mkf2(z[2].x * z[2].y, 0.f);   // bin N/2
            pointwise_pair(z[1], z[3]);          // 4096 <-> 12288
            bfly_dit1(z);
#pragma unroll
            for (int k = 0; k < 4; ++k) lds[k] = z[k];
            f2 w[4];
#pragma unroll
            for (int k = 0; k < 4; ++k) w[k] = lds[8 + k];
            bfly_dif1(w);
            pointwise_pair(w[0], w[3]);
            pointwise_pair(w[1], w[2]);
            bfly_dit1(w);
#pragma unroll
            for (int k = 0; k < 4; ++k) lds[8 + k] = w[k];
        } else {
            const int sA = swz(4 * rev4_12(p));
            const int sB = swz(4 * rev4_12(4096 - p));
            f2 A[4], B[4];
#pragma unroll
            for (int k = 0; k < 4; ++k) A[k] = lds[sA ^ k];
#pragma unroll
            for (int k = 0; k < 4; ++k) B[k] = lds[sB ^ k];
            bfly_dif1(A);
            bfly_dif1(B);
            pointwise_pair(A[0], B[3]);
            pointwise_pair(A[1], B[2]);
            pointwise_pair(A[2], B[1]);
            pointwise_pair(A[3], B[0]);
            bfly_dit1(A);
            bfly_dit1(B);
#pragma unroll
            for (int k = 0; k < 4; ++k) lds[sA ^ k] = A[k];
#pragma unroll
            for (int k = 0; k < 4; ++k) lds[sB ^ k] = B[k];
        }
    }
    __syncthreads();

    // ---- inv q=4&16 then q=64&256: both wave-local ----
    inv_pair<4>(lds, tid);
    asm volatile("" ::: "memory");
    inv_pair<64>(lds, tid);
    __syncthreads();

    // ---- fused q=1024&4096 + store (cross-wave) ----
    inv_last(lds, tid, out + (size_t)row * L_LEN);
}

extern "C" void kernel_launch(void* const* d_in, const int* in_sizes, int n_in,
                              void* d_out, int out_size, void* d_ws, size_t ws_size,
                              hipStream_t stream) {
    const float* x = (const float*)d_in[0];
    const float* h = (const float*)d_in[1];
    float* out = (float*)d_out;
    const int rows = in_sizes[0] / L_LEN;   // 2048
    fftconv_kernel<<<dim3(rows), dim3(NB), 0, stream>>>(x, h, out);
}

// Round 15
// 108.332 us; speedup vs baseline: 1.2731x; 1.0356x over previous
//
#include <hip/hip_runtime.h>

#define L_LEN 8192
#define N_FFT 16384   // 2*L
#define NB    1024

#define LB __launch_bounds__(NB)

// 2-wide float vector = one complex value (re, im).
typedef float f2 __attribute__((ext_vector_type(2)));

__device__ __forceinline__ f2 mkf2(float a, float b) { f2 v; v.x = a; v.y = b; return v; }

__device__ __forceinline__ f2 cmul(f2 a, f2 w) {
    return mkf2(a.y, a.y) * mkf2(-w.y, w.x) + mkf2(a.x, a.x) * w;
}

// Native hardware sin/cos in REVOLUTIONS; all twiddle args are exact dyadic
// rationals with |rev| <= 1/4, so no range reduction is needed.
__device__ __forceinline__ void sincos_rev(float rev, float* sn, float* cs) {
    *sn = __builtin_amdgcn_sinf(rev);
    *cs = __builtin_amdgcn_cosf(rev);
}
// vector-returning variant: (cos, sin) as one f2
__device__ __forceinline__ f2 cis_rev(float rev) {
    return mkf2(__builtin_amdgcn_cosf(rev), __builtin_amdgcn_sinf(rev));
}

// bijective GF(2)-linear LDS swizzle: swz(a^b)=swz(a)^swz(b) (disjoint fields).
__host__ __device__ constexpr int swz(int i) {
    return i ^ ((((i) >> 4) ^ ((i) >> 8) ^ ((i) >> 12)) & 15);
}

// reverse 6 base-4 digits (12-bit input)
__device__ __forceinline__ int rev6(int m) {
    int r = 0;
#pragma unroll
    for (int d = 0; d < 6; ++d) { r = (r << 2) | (m & 3); m >>= 2; }
    return r;
}

// DIF radix-4 butterfly (forward), twiddles precomputed.
__device__ __forceinline__ void bfly_dif(f2& x0, f2& x1, f2& x2, f2& x3,
                                         f2 w1, f2 w2, f2 w3) {
    f2 A = x0 + x2, B = x0 - x2, C = x1 + x3, D = x1 - x3;
    f2 iD = mkf2(-D.y, D.x);
    x0 = A + C;
    x1 = cmul(B - iD, w1);
    x2 = cmul(A - C, w2);
    x3 = cmul(B + iD, w3);
}

// DIT radix-4 butterfly (inverse): twiddle inputs then combine.
__device__ __forceinline__ void bfly_dit(f2& x0, f2& x1, f2& x2, f2& x3,
                                         f2 w1, f2 w2, f2 w3) {
    f2 a1 = cmul(x1, w1), a2 = cmul(x2, w2), a3 = cmul(x3, w3);
    f2 E = x0 + a2, F = x0 - a2, G = a1 + a3, K = a1 - a3;
    f2 iK = mkf2(-K.y, K.x);
    x0 = E + G; x1 = F + iK; x2 = E - G; x3 = F - iK;
}

__device__ __forceinline__ void bfly_dif1(f2* z) {
    f2 A = z[0] + z[2], B = z[0] - z[2], C = z[1] + z[3], D = z[1] - z[3];
    f2 iD = mkf2(-D.y, D.x);
    z[0] = A + C; z[1] = B - iD; z[2] = A - C; z[3] = B + iD;
}

// Y[m] = X[m]*H[m] from Z[m] (arg Zm) and Z[N-m] (arg Zr) of z = x + i*h.
__device__ __forceinline__ f2 pwY(f2 Zm, f2 Zr) {
    f2 half = mkf2(0.5f, 0.5f);
    f2 X = half * (Zm + mkf2(Zr.x, -Zr.y));
    f2 H = half * (mkf2(Zm.y, -Zm.x) + mkf2(Zr.y, Zr.x));
    return cmul(X, H);
}

// cos/sin of 2*pi*j/16, j=0..3
#define CT0 1.0f
#define CT1 0.92387953251128674f
#define CT2 0.70710678118654752f
#define CT3 0.38268343236508977f
#define ST1 0.38268343236508977f
#define ST2 0.70710678118654752f
#define ST3 0.92387953251128674f

// First forward double-stage (q=4096,1024) fused with global load; upper
// input half is the zero-pad (x2=x3=0 in the q=4096 butterfly).
__device__ __forceinline__ void fwd_first(f2* lds, int tid,
                                          const float* __restrict__ xr,
                                          const float* __restrict__ hr) {
    f2 r[4][4];
    float snA, csA;
    sincos_rev((float)tid * (-1.0f / 16384.f), &snA, &csA);
    f2 u1 = mkf2(csA, snA);
    const f2 lad[4] = {mkf2(CT0, 0.f), mkf2(CT1, -ST1), mkf2(CT2, -ST2), mkf2(CT3, -ST3)};
#pragma unroll
    for (int jB = 0; jB < 4; ++jB) {
        const int t = tid + jB * 1024;
        f2 z0 = mkf2(xr[t], hr[t]);
        f2 z1 = mkf2(xr[t + 4096], hr[t + 4096]);
        f2 w1 = (jB == 0) ? u1 : cmul(u1, lad[jB]);
        f2 w2 = cmul(w1, w1);
        f2 w3 = cmul(w2, w1);
        f2 iz1 = mkf2(-z1.y, z1.x);
        r[0][jB] = z0 + z1;
        r[1][jB] = cmul(z0 - iz1, w1);
        r[2][jB] = cmul(z0 - z1, w2);
        r[3][jB] = cmul(z0 + iz1, w3);
    }
    float sn, cs;
    sincos_rev((float)tid * (-1.0f / 4096.f), &sn, &cs);
    f2 v1 = mkf2(cs, sn);
    f2 v2 = cmul(v1, v1);
    f2 v3 = cmul(v2, v1);
#pragma unroll
    for (int jA = 0; jA < 4; ++jA)
        bfly_dif(r[jA][0], r[jA][1], r[jA][2], r[jA][3], v1, v2, v3);

    const int sb = swz(tid);
#pragma unroll
    for (int jA = 0; jA < 4; ++jA)
#pragma unroll
        for (int jB = 0; jB < 4; ++jB)
            lds[sb ^ swz(jA * 4096 + jB * 1024)] = r[jA][jB];
}

// Fused forward DIF pair: stage q=QA then q=QA/4.
template<int QA>
__device__ __forceinline__ void fwd_pair(f2* lds, int tid) {
    constexpr int QB = QA / 4;
    const int g = tid / QB;
    const int u = tid % QB;
    const int sb = swz(g * (4 * QA) + u);
    f2 r[4][4];
#pragma unroll
    for (int jA = 0; jA < 4; ++jA)
#pragma unroll
        for (int jB = 0; jB < 4; ++jB)
            r[jA][jB] = lds[sb ^ swz(jA * QA + jB * QB)];

    {
        float sn, cs;
        sincos_rev((float)u * (-1.0f / (float)(4 * QA)), &sn, &cs);
        f2 u1 = mkf2(cs, sn);
        const f2 lad[4] = {mkf2(CT0, 0.f), mkf2(CT1, -ST1), mkf2(CT2, -ST2), mkf2(CT3, -ST3)};
#pragma unroll
        for (int jB = 0; jB < 4; ++jB) {
            f2 w1 = (jB == 0) ? u1 : cmul(u1, lad[jB]);
            f2 w2 = cmul(w1, w1);
            f2 w3 = cmul(w2, w1);
            bfly_dif(r[0][jB], r[1][jB], r[2][jB], r[3][jB], w1, w2, w3);
        }
    }
    {
        float sn, cs;
        sincos_rev((float)u * (-1.0f / (float)(4 * QB)), &sn, &cs);
        f2 v1 = mkf2(cs, sn);
        f2 v2 = cmul(v1, v1);
        f2 v3 = cmul(v2, v1);
#pragma unroll
        for (int jA = 0; jA < 4; ++jA)
            bfly_dif(r[jA][0], r[jA][1], r[jA][2], r[jA][3], v1, v2, v3);
    }

#pragma unroll
    for (int jA = 0; jA < 4; ++jA)
#pragma unroll
        for (int jB = 0; jB < 4; ++jB)
            lds[sb ^ swz(jA * QA + jB * QB)] = r[jA][jB];
}

// ---- combo item: finish fwd (q=1), Y=XH, build Zi[j] for the half-size
// inverse: Zi[j] = (Y[j]+Y[j+8192]) + i e^{2pi i j/N} (Y[j]-Y[j+8192]).
// Quad A (base 4*rev6(b)) holds bins {b,4096+b,8192+b,12288+b}; quad B holds
// their mirrors. Produces Zi at j = {b, 4096+b, 4096-b, 8192-b}, stored at
// slot (j&1)*4096 + rev6(j>>1) (digit-reversed input for the 4096-IFFT halves).
__device__ __forceinline__ void combo_item(const f2* lds, int b, f2* Zi, int* sl) {
    const int sA = swz(4 * rev6(b));
    const int sB = swz(4 * rev6(4096 - b));
    f2 A[4], B[4];
#pragma unroll
    for (int k = 0; k < 4; ++k) { A[k] = lds[sA ^ k]; B[k] = lds[sB ^ k]; }
    bfly_dif1(A);
    bfly_dif1(B);
    f2 Yb   = pwY(A[0], B[3]);   // Y[b]
    f2 Yb4  = pwY(A[1], B[2]);   // Y[4096+b]
    f2 Yb8  = pwY(A[2], B[1]);   // Y[8192+b]
    f2 Yb12 = pwY(A[3], B[0]);   // Y[12288+b]
    f2 t = cis_rev((float)b * (1.0f / 16384.f));   // (cos, sin) = e^{+2pi i b/N}
    f2 S  = Yb + Yb8,   D  = Yb - Yb8;
    f2 Sp = Yb4 + Yb12, Dp = Yb4 - Yb12;
    f2 c  = cmul(D, t);
    f2 cp = cmul(Dp, t);
    Zi[0] = mkf2(S.x - c.y,    S.y + c.x);       // j = b        : S + i c
    Zi[1] = Sp - cp;                             // j = 4096+b   : t'=it
    Zi[2] = mkf2(Sp.x + cp.x, -(Sp.y + cp.y));   // j = 4096-b   : conj(Sp+cp)
    Zi[3] = mkf2(S.x + c.y,   -S.y + c.x);       // j = 8192-b   : conj(S)+i*conj(c)
    const int sbase = (b & 1) ? 4097 : 0;        // swz(par*4096)
    const int ra = rev6(b >> 1);                 // ra % 4 == 0
    const int rc = rev6((4096 - b) >> 1);        // rc % 4 in {0,1} (bit1 free)
    sl[0] = sbase ^ swz(ra);
    sl[1] = sl[0] ^ 2;                           // rev6(2048 + (b>>1)) = ra+2
    sl[2] = sbase ^ swz(rc);
    sl[3] = sl[2] ^ 2;                           // rev6(2048 + (4096-b)>>1) = rc+2
}

// specials: j in {0, 4096} (from quad a=0) and {2048, 6144} (quad a=2)
__device__ __forceinline__ void combo_special(const f2* lds, f2* Zi, int* sl) {
    f2 z[4];
#pragma unroll
    for (int k = 0; k < 4; ++k) z[k] = lds[k];       // quad 0: bins 0,4096,8192,12288
    bfly_dif1(z);
    float Y0 = z[0].x * z[0].y;                      // Y[0] (real)
    float Y8 = z[2].x * z[2].y;                      // Y[8192] (real)
    f2 Y4096 = pwY(z[1], z[3]);
    Zi[0] = mkf2(Y0 + Y8, Y0 - Y8);          sl[0] = 0;   // Zi[0], t=1
    Zi[1] = mkf2(2.f * Y4096.x, -2.f * Y4096.y); sl[1] = 2; // Zi[4096]=2conj(Y)
    f2 w[4];
#pragma unroll
    for (int k = 0; k < 4; ++k) w[k] = lds[8 + k];   // quad a=2: bins 2048,6144,10240,14336
    bfly_dif1(w);
    f2 Y2048 = pwY(w[0], w[3]);
    f2 Y6144 = pwY(w[1], w[2]);
    f2 cj6 = mkf2(Y6144.x, -Y6144.y);
    f2 S1 = Y2048 + cj6, D1 = Y2048 - cj6;
    f2 t1 = mkf2(0.70710678118654752f, 0.70710678118654752f);    // e^{i pi/4}
    f2 c1 = cmul(D1, t1);
    Zi[2] = mkf2(S1.x - c1.y, S1.y + c1.x);  sl[2] = 1;   // Zi[2048]
    f2 cj2 = mkf2(Y2048.x, -Y2048.y);
    f2 S2 = Y6144 + cj2, D2 = Y6144 - cj2;
    f2 t2 = mkf2(-0.70710678118654752f, 0.70710678118654752f);   // e^{3i pi/4}
    f2 c2 = cmul(D2, t2);
    Zi[3] = mkf2(S2.x - c2.y, S2.y + c2.x);  sl[3] = 3;   // Zi[6144]
}

// Fused inverse DIT pair (q=QA then 4*QA) on one 4096-point half.
// th in [0,512): half h=th>>8 (slot offset 4096h), within-half thread k.
template<int QA>
__device__ __forceinline__ void inv_half(f2* lds, int th) {
    constexpr int QB = 4 * QA;
    const int h = th >> 8;
    const int k = th & 255;
    const int g = k / QA, u = k % QA;
    const int base = g * (16 * QA) + u;
    const int sb = (h ? 4097 : 0) ^ swz(base);
    f2 r[4][4];
#pragma unroll
    for (int jA = 0; jA < 4; ++jA)
#pragma unroll
        for (int jB = 0; jB < 4; ++jB)
            r[jA][jB] = lds[sb ^ swz(jA * QA + jB * QB)];

    {   // stage A (q=QA) over jA, twiddle u/(4QA)
        f2 a1;
        if constexpr (QA == 1) a1 = mkf2(1.f, 0.f);
        else { float sn, cs; sincos_rev((float)u * (1.0f / (float)(4 * QA)), &sn, &cs); a1 = mkf2(cs, sn); }
        f2 a2 = cmul(a1, a1), a3 = cmul(a2, a1);
#pragma unroll
        for (int jB = 0; jB < 4; ++jB)
            bfly_dit(r[0][jB], r[1][jB], r[2][jB], r[3][jB], a1, a2, a3);
    }
    {   // stage B (q=QB) over jB, twiddle (u + jA*QA)/(16QA)
        f2 b1;
        if constexpr (QA == 1) b1 = mkf2(1.f, 0.f);
        else { float sn, cs; sincos_rev((float)u * (1.0f / (float)(16 * QA)), &sn, &cs); b1 = mkf2(cs, sn); }
        const f2 lad[4] = {mkf2(CT0, 0.f), mkf2(CT1, ST1), mkf2(CT2, ST2), mkf2(CT3, ST3)};
#pragma unroll
        for (int jA = 0; jA < 4; ++jA) {
            f2 w1 = (jA == 0) ? b1 : cmul(b1, lad[jA]);
            f2 w2 = cmul(w1, w1), w3 = cmul(w2, w1);
            bfly_dit(r[jA][0], r[jA][1], r[jA][2], r[jA][3], w1, w2, w3);
        }
    }
#pragma unroll
    for (int jA = 0; jA < 4; ++jA)
#pragma unroll
        for (int jB = 0; jB < 4; ++jB)
            lds[sb ^ swz(jA * QA + jB * QB)] = r[jA][jB];
}

// Final radix-2 (q=4096 over the two halves) + store. Only m<4096 needed:
// S[m] = P[m] + e^{2pi i m/8192} Q[m]; out[2m]=Re*sc, out[2m+1]=Im*sc.
__device__ __forceinline__ void inv_last(const f2* lds, int tid,
                                         float* __restrict__ orow) {
    const float sc = 1.0f / (16384.f * 16384.f);   // 2^-28
#pragma unroll
    for (int i = 0; i < 4; ++i) {
        const int m = tid + i * 1024;
        const int sm = swz(m);
        f2 P = lds[sm];
        f2 Q = lds[sm ^ 4097];          // swz(4096+m)
        f2 t = cis_rev((float)m * (1.0f / 8192.f));
        f2 w = P + cmul(Q, t);
        *(f2*)(orow + 2 * m) = mkf2(w.x * sc, w.y * sc);
    }
}

__global__ LB
void fftconv_kernel(const float* __restrict__ xin,
                    const float* __restrict__ hin,
                    float* __restrict__ out)
{
    __shared__ f2 lds[N_FFT];   // 128 KiB

    const int row = blockIdx.x;
    const int tid = threadIdx.x;
    const float* xr = xin + (size_t)row * L_LEN;
    const float* hr = hin + (size_t)row * L_LEN;

    // ---- forward (unchanged): fused load + q=4096&1024; 256&64; 16&4 ----
    fwd_first(lds, tid, xr, hr);
    __syncthreads();
    fwd_pair<256>(lds, tid);
    asm volatile("" ::: "memory");
    fwd_pair<16>(lds, tid);
    __syncthreads();

    // ---- combo: finish fwd q=1, Y=XH, build 8 Zi per thread in registers.
    // ALL loads complete before the barrier; ALL Zi stores after (read-set
    // and write-set differ, so the barrier separates them globally).
    {
        f2 Zi0[4], Zi1[4];
        int s0[4], s1[4];
        if (tid == 0) combo_special(lds, Zi0, s0);
        else          combo_item(lds, tid, Zi0, s0);
        combo_item(lds, tid + 1024, Zi1, s1);
        __syncthreads();
#pragma unroll
        for (int k = 0; k < 4; ++k) { lds[s0[k]] = Zi0[k]; lds[s1[k]] = Zi1[k]; }
    }
    __syncthreads();

    // ---- inverse: two independent 4096-point IFFTs (halves), 512 threads.
    // q=1&4 and q=16&64 are wave-local within 1024-slot blocks -> fence only.
    if (tid < 512) {
        inv_half<1>(lds, tid);
        asm volatile("" ::: "memory");
        inv_half<16>(lds, tid);
    }
    __syncthreads();
    if (tid < 512) inv_half<256>(lds, tid);
    __syncthreads();

    // ---- final radix-2 + scale + interleaved float2 store ----
    inv_last(lds, tid, out + (size_t)row * L_LEN);
}

extern "C" void kernel_launch(void* const* d_in, const int* in_sizes, int n_in,
                              void* d_out, int out_size, void* d_ws, size_t ws_size,
                              hipStream_t stream) {
    const float* x = (const float*)d_in[0];
    const float* h = (const float*)d_in[1];
    float* out = (float*)d_out;
    const int rows = in_sizes[0] / L_LEN;   // 2048
    fftconv_kernel<<<dim3(rows), dim3(NB), 0, stream>>>(x, h, out);
}